// Round 1
// baseline (4402.715 us; speedup 1.0000x reference)
//
#include <hip/hip_runtime.h>
#include <math.h>

#define BOX   256
#define KTAPS 9
#define HALF  4
#define NPTS  50000
#define LATD  10
#define NEUR  32
#define NLAY  3
#define BATCH 16

#define IMG_ELEMS (BATCH*BOX*BOX)                 // 1,048,576
#define OFF_IMG2  (IMG_ELEMS)                     // second img copy
#define OFF_PROJ  (2*IMG_ELEMS)                   // 2,097,152
#define OFF_POS   (OFF_PROJ + BATCH*NPTS*2)       // 3,697,152
#define OFF_RES   (OFF_POS  + BATCH*NPTS*3)       // 6,097,152

__global__ __launch_bounds__(256) void fused_fwd(
    const float* __restrict__ z, const float* __restrict__ r,
    const float* __restrict__ pos_param, const float* __restrict__ amp,
    const float* __restrict__ lin0_w, const float* __restrict__ deform_w,
    const float* __restrict__ deform_b, const float* __restrict__ lin1a_w,
    const float* __restrict__ lin1b_w, const float* __restrict__ linamp_w,
    const float* __restrict__ linamp_b, const int* __restrict__ dflag,
    float* __restrict__ out)
{
    __shared__ float s_lin0[NEUR*12];
    __shared__ float s_dw[NLAY*NEUR*NEUR];
    __shared__ float s_db[NLAY*NEUR];
    __shared__ float s_l1a[3*NEUR];
    __shared__ float s_l1b[9];
    __shared__ float s_z[LATD];
    __shared__ float s_r[9];

    const int b = blockIdx.y;
    for (int i = threadIdx.x; i < NEUR*12;        i += 256) s_lin0[i] = lin0_w[i];
    for (int i = threadIdx.x; i < NLAY*NEUR*NEUR; i += 256) s_dw[i]   = deform_w[i];
    for (int i = threadIdx.x; i < NLAY*NEUR;      i += 256) s_db[i]   = deform_b[i];
    for (int i = threadIdx.x; i < 3*NEUR;         i += 256) s_l1a[i]  = lin1a_w[i];
    if (threadIdx.x < 9)                       s_l1b[threadIdx.x]     = lin1b_w[threadIdx.x];
    if (threadIdx.x >= 16 && threadIdx.x < 26) s_z[threadIdx.x-16]    = z[b*LATD + threadIdx.x-16];
    if (threadIdx.x >= 32 && threadIdx.x < 41) s_r[threadIdx.x-32]    = r[b*9 + threadIdx.x-32];
    __syncthreads();

    const int n = blockIdx.x*256 + threadIdx.x;
    if (n >= NPTS) return;

    const float p0 = pos_param[n*3+0];
    const float p1 = pos_param[n*3+1];
    const float p2 = pos_param[n*3+2];

    float res0 = 0.f, res1 = 0.f, res2 = 0.f;
    if (*dflag > 0) {
        float h[NEUR];
        #pragma unroll
        for (int o = 0; o < NEUR; o++) {
            const float* w = &s_lin0[o*12];
            float acc = w[0]*p0;
            acc = fmaf(w[1], p1, acc);
            acc = fmaf(w[2], p2, acc);
            #pragma unroll
            for (int j = 0; j < LATD-1; j++) acc = fmaf(w[3+j], s_z[j], acc);
            h[o] = acc;
        }
        for (int l = 0; l < NLAY; l++) {
            float nh[NEUR];
            #pragma unroll
            for (int o = 0; o < NEUR; o++) {
                const float* w = &s_dw[(l*NEUR+o)*NEUR];
                float acc = s_db[l*NEUR+o];
                #pragma unroll
                for (int j = 0; j < NEUR; j++) acc = fmaf(w[j], h[j], acc);
                nh[o] = fmaxf(acc, 0.f) + h[o];
            }
            #pragma unroll
            for (int o = 0; o < NEUR; o++) h[o] = nh[o];
        }
        float t[3];
        #pragma unroll
        for (int o = 0; o < 3; o++) {
            const float* w = &s_l1a[o*NEUR];
            float acc = 0.f;
            #pragma unroll
            for (int j = 0; j < NEUR; j++) acc = fmaf(w[j], h[j], acc);
            t[o] = tanhf(acc);
        }
        // res[k] = sum_j t[j] * lin1b_w[k][j]
        res0 = fmaf(t[0], s_l1b[0], fmaf(t[1], s_l1b[1], t[2]*s_l1b[2]));
        res1 = fmaf(t[0], s_l1b[3], fmaf(t[1], s_l1b[4], t[2]*s_l1b[5]));
        res2 = fmaf(t[0], s_l1b[6], fmaf(t[1], s_l1b[7], t[2]*s_l1b[8]));
    }

    const float pos0 = p0 + res0, pos1 = p1 + res1, pos2 = p2 + res2;
    // proj[k] = sum_j pos[j] * r[b][j][k]
    const float proj0 = fmaf(pos0, s_r[0], fmaf(pos1, s_r[3], pos2*s_r[6]));
    const float proj1 = fmaf(pos0, s_r[1], fmaf(pos1, s_r[4], pos2*s_r[7]));

    // amp_corr = sigmoid(z[b, LAT-1]*linamp_w[n] + linamp_b[n])
    const float lo = fmaf(s_z[LATD-1], linamp_w[n], linamp_b[n]);
    const float acorr = 1.0f / (1.0f + expf(-lo));
    const float a = acorr * amp[0];

    const long long bn = (long long)b*NPTS + n;
    out[OFF_PROJ + bn*2 + 0] = proj0;
    out[OFF_PROJ + bn*2 + 1] = proj1;
    out[OFF_POS  + bn*3 + 0] = pos0;
    out[OFF_POS  + bn*3 + 1] = pos1;
    out[OFF_POS  + bn*3 + 2] = pos2;
    out[OFF_RES  + bn*3 + 0] = res0;
    out[OFF_RES  + bn*3 + 1] = res1;
    out[OFF_RES  + bn*3 + 2] = res2;

    // ---- splat ----
    const float px0 = (proj0 + 0.5f) * (float)(BOX-1);
    const float px1 = (proj1 + 0.5f) * (float)(BOX-1);
    const float c0 = floorf(px0 + 0.5f);
    const float c1 = floorf(px1 + 0.5f);
    const float inv2s2 = 1.0f/(2.0f*1.5f*1.5f);

    float w0[KTAPS], w1[KTAPS];
    int   i0[KTAPS], i1[KTAPS];
    #pragma unroll
    for (int k = 0; k < KTAPS; k++) {
        float g0 = c0 + (float)(k - HALF);
        float d0 = g0 - px0;
        float ww0 = expf(-d0*d0*inv2s2);
        if (g0 < 0.f || g0 > (float)(BOX-1)) ww0 = 0.f;
        w0[k] = ww0;
        i0[k] = (int)fminf(fmaxf(g0, 0.f), (float)(BOX-1));

        float g1 = c1 + (float)(k - HALF);
        float d1 = g1 - px1;
        float ww1 = expf(-d1*d1*inv2s2);
        if (g1 < 0.f || g1 > (float)(BOX-1)) ww1 = 0.f;
        w1[k] = ww1;
        i1[k] = (int)fminf(fmaxf(g1, 0.f), (float)(BOX-1));
    }

    float* img = out + (size_t)b*BOX*BOX;
    #pragma unroll
    for (int ky = 0; ky < KTAPS; ky++) {
        const float ay = a * w0[ky];
        float* rowp = img + i0[ky]*BOX;
        #pragma unroll
        for (int kx = 0; kx < KTAPS; kx++) {
            atomicAdd(&rowp[i1[kx]], ay * w1[kx]);
        }
    }
}

__global__ __launch_bounds__(256) void copy_img(const float4* __restrict__ src,
                                                float4* __restrict__ dst, int n4)
{
    int i = blockIdx.x*blockDim.x + threadIdx.x;
    if (i < n4) dst[i] = src[i];
}

extern "C" void kernel_launch(void* const* d_in, const int* in_sizes, int n_in,
                              void* d_out, int out_size, void* d_ws, size_t ws_size,
                              hipStream_t stream)
{
    const float* z        = (const float*)d_in[0];
    const float* r        = (const float*)d_in[1];
    const float* posp     = (const float*)d_in[2];
    const float* amp      = (const float*)d_in[3];
    const float* lin0_w   = (const float*)d_in[4];
    const float* deform_w = (const float*)d_in[5];
    const float* deform_b = (const float*)d_in[6];
    const float* lin1a_w  = (const float*)d_in[7];
    const float* lin1b_w  = (const float*)d_in[8];
    const float* linamp_w = (const float*)d_in[9];
    const float* linamp_b = (const float*)d_in[10];
    const int*   dflag    = (const int*)d_in[11];
    float* out = (float*)d_out;

    // zero the first image region (atomics accumulate into it)
    hipMemsetAsync(out, 0, (size_t)IMG_ELEMS*sizeof(float), stream);

    dim3 grid((NPTS + 255)/256, BATCH);
    fused_fwd<<<grid, 256, 0, stream>>>(z, r, posp, amp, lin0_w, deform_w, deform_b,
                                        lin1a_w, lin1b_w, linamp_w, linamp_b, dflag, out);

    const int n4 = IMG_ELEMS/4;
    copy_img<<<(n4 + 255)/256, 256, 0, stream>>>((const float4*)out,
                                                 (float4*)(out + OFF_IMG2), n4);
}

// Round 2
// 1042.825 us; speedup vs baseline: 4.2219x; 4.2219x over previous
//
#include <hip/hip_runtime.h>
#include <math.h>
#include <limits.h>

#define BOX   256
#define KTAPS 9
#define HALF  4
#define NPTS  50000
#define LATD  10
#define NEUR  32
#define NLAY  3
#define BATCH 16

#define TPB     256
#define PPT     4                    // points per thread
#define PTSBLK  (TPB*PPT)            // 1024 points per block
#define TILE_CAP 9600                // 37.5 KB LDS splat window (e.g. 97x97)

#define IMG_ELEMS (BATCH*BOX*BOX)                 // 1,048,576
#define OFF_IMG2  (IMG_ELEMS)
#define OFF_PROJ  (2*IMG_ELEMS)
#define OFF_POS   (OFF_PROJ + BATCH*NPTS*2)
#define OFF_RES   (OFF_POS  + BATCH*NPTS*3)

__global__ __launch_bounds__(TPB) void fused_fwd(
    const float* __restrict__ z, const float* __restrict__ r,
    const float* __restrict__ pos_param, const float* __restrict__ amp,
    const float* __restrict__ lin0_w, const float* __restrict__ deform_w,
    const float* __restrict__ deform_b, const float* __restrict__ lin1a_w,
    const float* __restrict__ lin1b_w, const float* __restrict__ linamp_w,
    const float* __restrict__ linamp_b, const int* __restrict__ dflag,
    float* __restrict__ out)
{
    __shared__ float s_lin0[NEUR*12];
    __shared__ float s_dw[NLAY*NEUR*NEUR];
    __shared__ float s_db[NLAY*NEUR];
    __shared__ float s_l1a[3*NEUR];
    __shared__ float s_l1b[9];
    __shared__ float s_z[LATD];
    __shared__ float s_r[9];
    __shared__ float tile[TILE_CAP];
    __shared__ int s_lo0, s_hi0, s_lo1, s_hi1;

    const int b   = blockIdx.y;
    const int tid = threadIdx.x;

    for (int i = tid; i < NEUR*12;        i += TPB) s_lin0[i] = lin0_w[i];
    for (int i = tid; i < NLAY*NEUR*NEUR; i += TPB) s_dw[i]   = deform_w[i];
    for (int i = tid; i < NLAY*NEUR;      i += TPB) s_db[i]   = deform_b[i];
    for (int i = tid; i < 3*NEUR;         i += TPB) s_l1a[i]  = lin1a_w[i];
    if (tid < 9)                s_l1b[tid]    = lin1b_w[tid];
    if (tid >= 16 && tid < 26)  s_z[tid-16]   = z[b*LATD + tid-16];
    if (tid >= 32 && tid < 41)  s_r[tid-32]   = r[b*9 + tid-32];
    if (tid == 0) { s_lo0 = INT_MAX; s_hi0 = INT_MIN; s_lo1 = INT_MAX; s_hi1 = INT_MIN; }
    for (int i = tid; i < TILE_CAP; i += TPB) tile[i] = 0.f;
    __syncthreads();

    const int   dd   = *dflag;
    const float ampv = amp[0];
    const int   base = blockIdx.x * PTSBLK;

    float sx[PPT], sy[PPT], sa[PPT];
    int lmin0 = INT_MAX, lmax0 = INT_MIN, lmin1 = INT_MAX, lmax1 = INT_MIN;

    // ---- pass 1: MLP + outputs + window bounds ----
    for (int p = 0; p < PPT; p++) {
        sa[p] = 0.f; sx[p] = 0.f; sy[p] = 0.f;
        const int n = base + p*TPB + tid;
        if (n >= NPTS) continue;

        const float p0 = pos_param[n*3+0];
        const float p1 = pos_param[n*3+1];
        const float p2 = pos_param[n*3+2];

        float res0 = 0.f, res1 = 0.f, res2 = 0.f;
        if (dd > 0) {
            float h[NEUR];
            #pragma unroll
            for (int o = 0; o < NEUR; o++) {
                const float* w = &s_lin0[o*12];
                float acc = w[0]*p0;
                acc = fmaf(w[1], p1, acc);
                acc = fmaf(w[2], p2, acc);
                #pragma unroll
                for (int j = 0; j < LATD-1; j++) acc = fmaf(w[3+j], s_z[j], acc);
                h[o] = acc;
            }
            for (int l = 0; l < NLAY; l++) {
                float nh[NEUR];
                #pragma unroll
                for (int o = 0; o < NEUR; o++) {
                    const float* w = &s_dw[(l*NEUR+o)*NEUR];
                    float acc = s_db[l*NEUR+o];
                    #pragma unroll
                    for (int j = 0; j < NEUR; j++) acc = fmaf(w[j], h[j], acc);
                    nh[o] = fmaxf(acc, 0.f) + h[o];
                }
                #pragma unroll
                for (int o = 0; o < NEUR; o++) h[o] = nh[o];
            }
            float t[3];
            #pragma unroll
            for (int o = 0; o < 3; o++) {
                const float* w = &s_l1a[o*NEUR];
                float acc = 0.f;
                #pragma unroll
                for (int j = 0; j < NEUR; j++) acc = fmaf(w[j], h[j], acc);
                t[o] = tanhf(acc);
            }
            res0 = fmaf(t[0], s_l1b[0], fmaf(t[1], s_l1b[1], t[2]*s_l1b[2]));
            res1 = fmaf(t[0], s_l1b[3], fmaf(t[1], s_l1b[4], t[2]*s_l1b[5]));
            res2 = fmaf(t[0], s_l1b[6], fmaf(t[1], s_l1b[7], t[2]*s_l1b[8]));
        }

        const float pos0 = p0 + res0, pos1 = p1 + res1, pos2 = p2 + res2;
        const float proj0 = fmaf(pos0, s_r[0], fmaf(pos1, s_r[3], pos2*s_r[6]));
        const float proj1 = fmaf(pos0, s_r[1], fmaf(pos1, s_r[4], pos2*s_r[7]));

        const float lo = fmaf(s_z[LATD-1], linamp_w[n], linamp_b[n]);
        const float acorr = 1.0f / (1.0f + expf(-lo));

        const long long bn = (long long)b*NPTS + n;
        out[OFF_PROJ + bn*2 + 0] = proj0;
        out[OFF_PROJ + bn*2 + 1] = proj1;
        out[OFF_POS  + bn*3 + 0] = pos0;
        out[OFF_POS  + bn*3 + 1] = pos1;
        out[OFF_POS  + bn*3 + 2] = pos2;
        out[OFF_RES  + bn*3 + 0] = res0;
        out[OFF_RES  + bn*3 + 1] = res1;
        out[OFF_RES  + bn*3 + 2] = res2;

        const float px0 = (proj0 + 0.5f) * (float)(BOX-1);
        const float px1 = (proj1 + 0.5f) * (float)(BOX-1);
        sx[p] = px0; sy[p] = px1; sa[p] = acorr * ampv;

        const float c0 = floorf(px0 + 0.5f);
        const float c1 = floorf(px1 + 0.5f);
        const int il0 = (int)fminf(fmaxf(c0 - (float)HALF, 0.f), (float)(BOX-1));
        const int ih0 = (int)fminf(fmaxf(c0 + (float)HALF, 0.f), (float)(BOX-1));
        const int il1 = (int)fminf(fmaxf(c1 - (float)HALF, 0.f), (float)(BOX-1));
        const int ih1 = (int)fminf(fmaxf(c1 + (float)HALF, 0.f), (float)(BOX-1));
        lmin0 = min(lmin0, il0); lmax0 = max(lmax0, ih0);
        lmin1 = min(lmin1, il1); lmax1 = max(lmax1, ih1);
    }
    if (lmin0 != INT_MAX) {
        atomicMin(&s_lo0, lmin0); atomicMax(&s_hi0, lmax0);
        atomicMin(&s_lo1, lmin1); atomicMax(&s_hi1, lmax1);
    }
    __syncthreads();

    const int lo0 = s_lo0, lo1 = s_lo1;
    const int W0 = s_hi0 - lo0 + 1, W1 = s_hi1 - lo1 + 1;
    const bool lds_ok = (s_hi0 >= lo0) && (W0 * W1 <= TILE_CAP);
    float* img = out + (size_t)b*BOX*BOX;
    const float inv2s2 = 1.0f/(2.0f*1.5f*1.5f);

    // ---- pass 2: splat taps ----
    for (int p = 0; p < PPT; p++) {
        const float aamp = sa[p];
        if (aamp == 0.f) continue;           // invalid or zero-contribution point
        const float px0 = sx[p], px1 = sy[p];
        const float c0 = floorf(px0 + 0.5f);
        const float c1 = floorf(px1 + 0.5f);

        float w0a[KTAPS], w1a[KTAPS];
        int   i0a[KTAPS], i1a[KTAPS];
        #pragma unroll
        for (int k = 0; k < KTAPS; k++) {
            float g0 = c0 + (float)(k - HALF);
            float d0 = g0 - px0;
            float ww0 = expf(-d0*d0*inv2s2);
            if (g0 < 0.f || g0 > (float)(BOX-1)) ww0 = 0.f;
            w0a[k] = ww0;
            i0a[k] = (int)fminf(fmaxf(g0, 0.f), (float)(BOX-1));

            float g1 = c1 + (float)(k - HALF);
            float d1 = g1 - px1;
            float ww1 = expf(-d1*d1*inv2s2);
            if (g1 < 0.f || g1 > (float)(BOX-1)) ww1 = 0.f;
            w1a[k] = ww1;
            i1a[k] = (int)fminf(fmaxf(g1, 0.f), (float)(BOX-1));
        }

        if (lds_ok) {
            #pragma unroll
            for (int ky = 0; ky < KTAPS; ky++) {
                const float ay = aamp * w0a[ky];
                const int rbase = (i0a[ky] - lo0)*W1 - lo1;
                #pragma unroll
                for (int kx = 0; kx < KTAPS; kx++)
                    atomicAdd(&tile[rbase + i1a[kx]], ay * w1a[kx]);
            }
        } else {
            #pragma unroll
            for (int ky = 0; ky < KTAPS; ky++) {
                const float ay = aamp * w0a[ky];
                float* rowp = img + i0a[ky]*BOX;
                #pragma unroll
                for (int kx = 0; kx < KTAPS; kx++)
                    atomicAdd(&rowp[i1a[kx]], ay * w1a[kx]);
            }
        }
    }

    __syncthreads();

    // ---- flush window to global ----
    if (lds_ok) {
        const int W = W0 * W1;
        for (int idx = tid; idx < W; idx += TPB) {
            const float v = tile[idx];
            if (v != 0.f) {
                const int rr = idx / W1;
                const int cc = idx - rr*W1;
                atomicAdd(&img[(lo0 + rr)*BOX + lo1 + cc], v);
            }
        }
    }
}

__global__ __launch_bounds__(256) void copy_img(const float4* __restrict__ src,
                                                float4* __restrict__ dst, int n4)
{
    int i = blockIdx.x*blockDim.x + threadIdx.x;
    if (i < n4) dst[i] = src[i];
}

extern "C" void kernel_launch(void* const* d_in, const int* in_sizes, int n_in,
                              void* d_out, int out_size, void* d_ws, size_t ws_size,
                              hipStream_t stream)
{
    const float* z        = (const float*)d_in[0];
    const float* r        = (const float*)d_in[1];
    const float* posp     = (const float*)d_in[2];
    const float* amp      = (const float*)d_in[3];
    const float* lin0_w   = (const float*)d_in[4];
    const float* deform_w = (const float*)d_in[5];
    const float* deform_b = (const float*)d_in[6];
    const float* lin1a_w  = (const float*)d_in[7];
    const float* lin1b_w  = (const float*)d_in[8];
    const float* linamp_w = (const float*)d_in[9];
    const float* linamp_b = (const float*)d_in[10];
    const int*   dflag    = (const int*)d_in[11];
    float* out = (float*)d_out;

    // zero the first image region (atomics accumulate into it)
    hipMemsetAsync(out, 0, (size_t)IMG_ELEMS*sizeof(float), stream);

    dim3 grid((NPTS + PTSBLK - 1)/PTSBLK, BATCH);
    fused_fwd<<<grid, TPB, 0, stream>>>(z, r, posp, amp, lin0_w, deform_w, deform_b,
                                        lin1a_w, lin1b_w, linamp_w, linamp_b, dflag, out);

    const int n4 = IMG_ELEMS/4;
    copy_img<<<(n4 + 255)/256, 256, 0, stream>>>((const float4*)out,
                                                 (float4*)(out + OFF_IMG2), n4);
}

// Round 3
// 655.125 us; speedup vs baseline: 6.7204x; 1.5918x over previous
//
#include <hip/hip_runtime.h>
#include <math.h>
#include <limits.h>

#define BOX   256
#define KTAPS 9
#define HALF  4
#define NPTS  50000
#define LATD  10
#define NEUR  32
#define NLAY  3
#define BATCH 16

#define TPB     256
#define PPT     4                    // points per thread
#define PTSBLK  (TPB*PPT)            // 1024 points per block
#define TILE_CAP 9600                // 37.5 KB LDS splat window (e.g. 97x97)

#define IMG_ELEMS (BATCH*BOX*BOX)                 // 1,048,576
#define OFF_IMG2  (IMG_ELEMS)
#define OFF_PROJ  (2*IMG_ELEMS)
#define OFF_POS   (OFF_PROJ + BATCH*NPTS*2)
#define OFF_RES   (OFF_POS  + BATCH*NPTS*3)

// fast tanh: 1 - 2/(e^{2x}+1)   (abs err ~1e-7, fine vs harness threshold)
__device__ __forceinline__ float fast_tanh(float x) {
    return 1.0f - 2.0f / (__expf(2.0f * x) + 1.0f);
}

__global__ __launch_bounds__(TPB) void fused_fwd(
    const float* __restrict__ z, const float* __restrict__ r,
    const float* __restrict__ pos_param, const float* __restrict__ amp,
    const float* __restrict__ lin0_w, const float* __restrict__ deform_w,
    const float* __restrict__ deform_b, const float* __restrict__ lin1a_w,
    const float* __restrict__ lin1b_w, const float* __restrict__ linamp_w,
    const float* __restrict__ linamp_b, const int* __restrict__ dflag,
    float* __restrict__ out)
{
    __shared__ float tile[TILE_CAP];
    __shared__ int s_lo0, s_hi0, s_lo1, s_hi1;

    const int b   = blockIdx.y;
    const int tid = threadIdx.x;

    if (tid == 0) { s_lo0 = INT_MAX; s_hi0 = INT_MIN; s_lo1 = INT_MAX; s_hi1 = INT_MIN; }
    for (int i = tid; i < TILE_CAP; i += TPB) tile[i] = 0.f;
    __syncthreads();

    const int   dd   = *dflag;
    const float ampv = amp[0];
    const float zlast = z[b*LATD + LATD-1];

    // rotation (only columns 0,1 used for projection) — wave-uniform s_loads
    const float r00 = r[b*9+0], r01 = r[b*9+1];
    const float r10 = r[b*9+3], r11 = r[b*9+4];
    const float r20 = r[b*9+6], r21 = r[b*9+7];

    // point-independent part of lin0:  zpart[o] = sum_j lin0_w[o][3+j]*z[b][j]
    float zpart[NEUR];
    if (dd > 0) {
        #pragma unroll
        for (int o = 0; o < NEUR; o++) {
            float acc = 0.f;
            #pragma unroll
            for (int j = 0; j < LATD-1; j++)
                acc = fmaf(lin0_w[o*12 + 3 + j], z[b*LATD + j], acc);
            zpart[o] = acc;
        }
    }

    const int base = blockIdx.x * PTSBLK;

    float sx[PPT], sy[PPT], sa[PPT];
    int lmin0 = INT_MAX, lmax0 = INT_MIN, lmin1 = INT_MAX, lmax1 = INT_MIN;

    // ---- pass 1: MLP + outputs + window bounds ----
    for (int p = 0; p < PPT; p++) {
        sa[p] = 0.f; sx[p] = 0.f; sy[p] = 0.f;
        const int n = base + p*TPB + tid;
        if (n >= NPTS) continue;

        const float p0 = pos_param[n*3+0];
        const float p1 = pos_param[n*3+1];
        const float p2 = pos_param[n*3+2];

        float res0 = 0.f, res1 = 0.f, res2 = 0.f;
        if (dd > 0) {
            float h[NEUR];
            #pragma unroll
            for (int o = 0; o < NEUR; o++) {
                float acc = zpart[o];
                acc = fmaf(lin0_w[o*12+0], p0, acc);
                acc = fmaf(lin0_w[o*12+1], p1, acc);
                acc = fmaf(lin0_w[o*12+2], p2, acc);
                h[o] = acc;
            }
            #pragma unroll
            for (int l = 0; l < NLAY; l++) {
                float nh[NEUR];
                #pragma unroll
                for (int o = 0; o < NEUR; o++) {
                    float acc = deform_b[l*NEUR + o];
                    #pragma unroll
                    for (int j = 0; j < NEUR; j++)
                        acc = fmaf(deform_w[(l*NEUR + o)*NEUR + j], h[j], acc);
                    nh[o] = fmaxf(acc, 0.f) + h[o];
                }
                #pragma unroll
                for (int o = 0; o < NEUR; o++) h[o] = nh[o];
            }
            float t0 = 0.f, t1 = 0.f, t2 = 0.f;
            #pragma unroll
            for (int j = 0; j < NEUR; j++) {
                t0 = fmaf(lin1a_w[0*NEUR + j], h[j], t0);
                t1 = fmaf(lin1a_w[1*NEUR + j], h[j], t1);
                t2 = fmaf(lin1a_w[2*NEUR + j], h[j], t2);
            }
            t0 = fast_tanh(t0); t1 = fast_tanh(t1); t2 = fast_tanh(t2);
            res0 = fmaf(t0, lin1b_w[0], fmaf(t1, lin1b_w[1], t2*lin1b_w[2]));
            res1 = fmaf(t0, lin1b_w[3], fmaf(t1, lin1b_w[4], t2*lin1b_w[5]));
            res2 = fmaf(t0, lin1b_w[6], fmaf(t1, lin1b_w[7], t2*lin1b_w[8]));
        }

        const float pos0 = p0 + res0, pos1 = p1 + res1, pos2 = p2 + res2;
        const float proj0 = fmaf(pos0, r00, fmaf(pos1, r10, pos2*r20));
        const float proj1 = fmaf(pos0, r01, fmaf(pos1, r11, pos2*r21));

        const float lo = fmaf(zlast, linamp_w[n], linamp_b[n]);
        const float acorr = 1.0f / (1.0f + __expf(-lo));

        const long long bn = (long long)b*NPTS + n;
        out[OFF_PROJ + bn*2 + 0] = proj0;
        out[OFF_PROJ + bn*2 + 1] = proj1;
        out[OFF_POS  + bn*3 + 0] = pos0;
        out[OFF_POS  + bn*3 + 1] = pos1;
        out[OFF_POS  + bn*3 + 2] = pos2;
        out[OFF_RES  + bn*3 + 0] = res0;
        out[OFF_RES  + bn*3 + 1] = res1;
        out[OFF_RES  + bn*3 + 2] = res2;

        const float px0 = (proj0 + 0.5f) * (float)(BOX-1);
        const float px1 = (proj1 + 0.5f) * (float)(BOX-1);
        sx[p] = px0; sy[p] = px1; sa[p] = acorr * ampv;

        const float c0 = floorf(px0 + 0.5f);
        const float c1 = floorf(px1 + 0.5f);
        const int il0 = (int)fminf(fmaxf(c0 - (float)HALF, 0.f), (float)(BOX-1));
        const int ih0 = (int)fminf(fmaxf(c0 + (float)HALF, 0.f), (float)(BOX-1));
        const int il1 = (int)fminf(fmaxf(c1 - (float)HALF, 0.f), (float)(BOX-1));
        const int ih1 = (int)fminf(fmaxf(c1 + (float)HALF, 0.f), (float)(BOX-1));
        lmin0 = min(lmin0, il0); lmax0 = max(lmax0, ih0);
        lmin1 = min(lmin1, il1); lmax1 = max(lmax1, ih1);
    }
    if (lmin0 != INT_MAX) {
        atomicMin(&s_lo0, lmin0); atomicMax(&s_hi0, lmax0);
        atomicMin(&s_lo1, lmin1); atomicMax(&s_hi1, lmax1);
    }
    __syncthreads();

    const int lo0 = s_lo0, lo1 = s_lo1;
    const int W0 = s_hi0 - lo0 + 1, W1 = s_hi1 - lo1 + 1;
    const bool lds_ok = (s_hi0 >= lo0) && (W0 * W1 <= TILE_CAP);
    float* img = out + (size_t)b*BOX*BOX;
    const float inv2s2 = 1.0f/(2.0f*1.5f*1.5f);

    // ---- pass 2: splat taps ----
    for (int p = 0; p < PPT; p++) {
        const float aamp = sa[p];
        if (aamp == 0.f) continue;
        const float px0 = sx[p], px1 = sy[p];
        const float c0 = floorf(px0 + 0.5f);
        const float c1 = floorf(px1 + 0.5f);

        float w0a[KTAPS], w1a[KTAPS];
        int   i0a[KTAPS], i1a[KTAPS];
        #pragma unroll
        for (int k = 0; k < KTAPS; k++) {
            float g0 = c0 + (float)(k - HALF);
            float d0 = g0 - px0;
            float ww0 = __expf(-d0*d0*inv2s2);
            if (g0 < 0.f || g0 > (float)(BOX-1)) ww0 = 0.f;
            w0a[k] = ww0;
            i0a[k] = (int)fminf(fmaxf(g0, 0.f), (float)(BOX-1));

            float g1 = c1 + (float)(k - HALF);
            float d1 = g1 - px1;
            float ww1 = __expf(-d1*d1*inv2s2);
            if (g1 < 0.f || g1 > (float)(BOX-1)) ww1 = 0.f;
            w1a[k] = ww1;
            i1a[k] = (int)fminf(fmaxf(g1, 0.f), (float)(BOX-1));
        }

        if (lds_ok) {
            #pragma unroll
            for (int ky = 0; ky < KTAPS; ky++) {
                const float ay = aamp * w0a[ky];
                const int rbase = (i0a[ky] - lo0)*W1 - lo1;
                #pragma unroll
                for (int kx = 0; kx < KTAPS; kx++)
                    atomicAdd(&tile[rbase + i1a[kx]], ay * w1a[kx]);
            }
        } else {
            #pragma unroll
            for (int ky = 0; ky < KTAPS; ky++) {
                const float ay = aamp * w0a[ky];
                float* rowp = img + i0a[ky]*BOX;
                #pragma unroll
                for (int kx = 0; kx < KTAPS; kx++)
                    atomicAdd(&rowp[i1a[kx]], ay * w1a[kx]);
            }
        }
    }

    __syncthreads();

    // ---- flush window to global ----
    if (lds_ok) {
        const int W = W0 * W1;
        for (int idx = tid; idx < W; idx += TPB) {
            const float v = tile[idx];
            if (v != 0.f) {
                const int rr = idx / W1;
                const int cc = idx - rr*W1;
                atomicAdd(&img[(lo0 + rr)*BOX + lo1 + cc], v);
            }
        }
    }
}

__global__ __launch_bounds__(256) void copy_img(const float4* __restrict__ src,
                                                float4* __restrict__ dst, int n4)
{
    int i = blockIdx.x*blockDim.x + threadIdx.x;
    if (i < n4) dst[i] = src[i];
}

extern "C" void kernel_launch(void* const* d_in, const int* in_sizes, int n_in,
                              void* d_out, int out_size, void* d_ws, size_t ws_size,
                              hipStream_t stream)
{
    const float* z        = (const float*)d_in[0];
    const float* r        = (const float*)d_in[1];
    const float* posp     = (const float*)d_in[2];
    const float* amp      = (const float*)d_in[3];
    const float* lin0_w   = (const float*)d_in[4];
    const float* deform_w = (const float*)d_in[5];
    const float* deform_b = (const float*)d_in[6];
    const float* lin1a_w  = (const float*)d_in[7];
    const float* lin1b_w  = (const float*)d_in[8];
    const float* linamp_w = (const float*)d_in[9];
    const float* linamp_b = (const float*)d_in[10];
    const int*   dflag    = (const int*)d_in[11];
    float* out = (float*)d_out;

    hipMemsetAsync(out, 0, (size_t)IMG_ELEMS*sizeof(float), stream);

    dim3 grid((NPTS + PTSBLK - 1)/PTSBLK, BATCH);
    fused_fwd<<<grid, TPB, 0, stream>>>(z, r, posp, amp, lin0_w, deform_w, deform_b,
                                        lin1a_w, lin1b_w, linamp_w, linamp_b, dflag, out);

    const int n4 = IMG_ELEMS/4;
    copy_img<<<(n4 + 255)/256, 256, 0, stream>>>((const float4*)out,
                                                 (float4*)(out + OFF_IMG2), n4);
}

// Round 4
// 609.020 us; speedup vs baseline: 7.2292x; 1.0757x over previous
//
#include <hip/hip_runtime.h>
#include <math.h>
#include <limits.h>

#define BOX   256
#define KTAPS 9
#define HALF  4
#define NPTS  50000
#define LATD  10
#define NEUR  32
#define NLAY  3
#define BATCH 16

#define ATPB  256
#define ABLKX ((NPTS + ATPB - 1)/ATPB)     // 196

#define BTPB  256
#define BPPT  8
#define BPTS  (BTPB*BPPT)                  // 2048 points per splat block
#define BBLKX ((NPTS + BPTS - 1)/BPTS)     // 25
#define TILE_CAP 9600                      // 37.5 KB LDS splat window

#define IMG_ELEMS (BATCH*BOX*BOX)          // 1,048,576
#define OFF_IMG2  (IMG_ELEMS)
#define OFF_PROJ  (2*IMG_ELEMS)
#define OFF_POS   (OFF_PROJ + BATCH*NPTS*2)
#define OFF_RES   (OFF_POS  + BATCH*NPTS*3)

__device__ __forceinline__ float fast_tanh(float x) {
    return 1.0f - 2.0f / (__expf(2.0f * x) + 1.0f);
}

// ---------------- kernel A: per-point MLP + outputs ----------------
__global__ __launch_bounds__(ATPB) void mlp_fwd(
    const float* __restrict__ z, const float* __restrict__ r,
    const float* __restrict__ pos_param,
    const float* __restrict__ lin0_w, const float* __restrict__ deform_w,
    const float* __restrict__ deform_b, const float* __restrict__ lin1a_w,
    const float* __restrict__ lin1b_w, const int* __restrict__ dflag,
    float* __restrict__ out)
{
    __shared__ float s_zpart[NEUR];
    const int b = blockIdx.y, tid = threadIdx.x;

    // point-independent part of lin0 (per block, 32 threads)
    if (tid < NEUR) {
        float acc = 0.f;
        #pragma unroll
        for (int j = 0; j < LATD-1; j++)
            acc = fmaf(lin0_w[tid*12 + 3 + j], z[b*LATD + j], acc);
        s_zpart[tid] = acc;
    }
    __syncthreads();

    const int n = blockIdx.x*ATPB + tid;
    if (n >= NPTS) return;
    const int dd = *dflag;

    const float r00 = r[b*9+0], r01 = r[b*9+1];
    const float r10 = r[b*9+3], r11 = r[b*9+4];
    const float r20 = r[b*9+6], r21 = r[b*9+7];

    const float p0 = pos_param[n*3+0];
    const float p1 = pos_param[n*3+1];
    const float p2 = pos_param[n*3+2];

    float res0 = 0.f, res1 = 0.f, res2 = 0.f;
    if (dd > 0) {
        float h[NEUR], nh[NEUR];
        #pragma unroll
        for (int o = 0; o < NEUR; o++) {
            float acc = s_zpart[o];
            acc = fmaf(lin0_w[o*12+0], p0, acc);
            acc = fmaf(lin0_w[o*12+1], p1, acc);
            acc = fmaf(lin0_w[o*12+2], p2, acc);
            h[o] = acc;
        }
        // rolled layer loop: body ~1.2k instr, fits I$; weights go via s_load
        #pragma unroll 1
        for (int l = 0; l < NLAY; l++) {
            const float* __restrict__ W  = deform_w + l*NEUR*NEUR;
            const float* __restrict__ bb = deform_b + l*NEUR;
            #pragma unroll
            for (int o = 0; o < NEUR; o++) {
                float acc = bb[o];
                #pragma unroll
                for (int j = 0; j < NEUR; j++)
                    acc = fmaf(W[o*NEUR + j], h[j], acc);
                nh[o] = fmaxf(acc, 0.f) + h[o];
            }
            #pragma unroll
            for (int o = 0; o < NEUR; o++) h[o] = nh[o];
        }
        float t0 = 0.f, t1 = 0.f, t2 = 0.f;
        #pragma unroll
        for (int j = 0; j < NEUR; j++) {
            t0 = fmaf(lin1a_w[0*NEUR + j], h[j], t0);
            t1 = fmaf(lin1a_w[1*NEUR + j], h[j], t1);
            t2 = fmaf(lin1a_w[2*NEUR + j], h[j], t2);
        }
        t0 = fast_tanh(t0); t1 = fast_tanh(t1); t2 = fast_tanh(t2);
        res0 = fmaf(t0, lin1b_w[0], fmaf(t1, lin1b_w[1], t2*lin1b_w[2]));
        res1 = fmaf(t0, lin1b_w[3], fmaf(t1, lin1b_w[4], t2*lin1b_w[5]));
        res2 = fmaf(t0, lin1b_w[6], fmaf(t1, lin1b_w[7], t2*lin1b_w[8]));
    }

    const float pos0 = p0 + res0, pos1 = p1 + res1, pos2 = p2 + res2;
    const float proj0 = fmaf(pos0, r00, fmaf(pos1, r10, pos2*r20));
    const float proj1 = fmaf(pos0, r01, fmaf(pos1, r11, pos2*r21));

    const long long bn = (long long)b*NPTS + n;
    out[OFF_PROJ + bn*2 + 0] = proj0;
    out[OFF_PROJ + bn*2 + 1] = proj1;
    out[OFF_POS  + bn*3 + 0] = pos0;
    out[OFF_POS  + bn*3 + 1] = pos1;
    out[OFF_POS  + bn*3 + 2] = pos2;
    out[OFF_RES  + bn*3 + 0] = res0;
    out[OFF_RES  + bn*3 + 1] = res1;
    out[OFF_RES  + bn*3 + 2] = res2;
}

// ---------------- kernel B: splat (reads proj back from out) ----------------
__global__ __launch_bounds__(BTPB) void splat(
    const float* __restrict__ z, const float* __restrict__ amp,
    const float* __restrict__ linamp_w, const float* __restrict__ linamp_b,
    float* __restrict__ out)
{
    __shared__ float tile[TILE_CAP];
    __shared__ int s_lo0, s_hi0, s_lo1, s_hi1;

    const int b = blockIdx.y, tid = threadIdx.x;
    if (tid == 0) { s_lo0 = INT_MAX; s_hi0 = INT_MIN; s_lo1 = INT_MAX; s_hi1 = INT_MIN; }
    for (int i = tid; i < TILE_CAP; i += BTPB) tile[i] = 0.f;

    const float ampv  = amp[0];
    const float zlast = z[b*LATD + LATD-1];
    const float* __restrict__ proj = out + OFF_PROJ;
    const int base = blockIdx.x * BPTS;

    float spx[BPPT], spy[BPPT], sa[BPPT];
    int lmin0 = INT_MAX, lmax0 = INT_MIN, lmin1 = INT_MAX, lmax1 = INT_MIN;

    #pragma unroll
    for (int p = 0; p < BPPT; p++) {
        sa[p] = 0.f; spx[p] = 0.f; spy[p] = 0.f;
        const int n = base + p*BTPB + tid;
        if (n >= NPTS) continue;
        const long long bn = (long long)b*NPTS + n;
        const float proj0 = proj[bn*2 + 0];
        const float proj1 = proj[bn*2 + 1];
        const float lo = fmaf(zlast, linamp_w[n], linamp_b[n]);
        sa[p] = ampv / (1.0f + __expf(-lo));

        const float px0 = (proj0 + 0.5f) * (float)(BOX-1);
        const float px1 = (proj1 + 0.5f) * (float)(BOX-1);
        spx[p] = px0; spy[p] = px1;
        const float c0 = floorf(px0 + 0.5f);
        const float c1 = floorf(px1 + 0.5f);
        const int il0 = (int)fminf(fmaxf(c0 - (float)HALF, 0.f), (float)(BOX-1));
        const int ih0 = (int)fminf(fmaxf(c0 + (float)HALF, 0.f), (float)(BOX-1));
        const int il1 = (int)fminf(fmaxf(c1 - (float)HALF, 0.f), (float)(BOX-1));
        const int ih1 = (int)fminf(fmaxf(c1 + (float)HALF, 0.f), (float)(BOX-1));
        lmin0 = min(lmin0, il0); lmax0 = max(lmax0, ih0);
        lmin1 = min(lmin1, il1); lmax1 = max(lmax1, ih1);
    }
    __syncthreads();   // tile zeroed; bounds vars initialized
    if (lmin0 != INT_MAX) {
        atomicMin(&s_lo0, lmin0); atomicMax(&s_hi0, lmax0);
        atomicMin(&s_lo1, lmin1); atomicMax(&s_hi1, lmax1);
    }
    __syncthreads();

    const int lo0 = s_lo0, lo1 = s_lo1;
    const int W0 = s_hi0 - lo0 + 1, W1 = s_hi1 - lo1 + 1;
    const bool lds_ok = (s_hi0 >= lo0) && (W0 * W1 <= TILE_CAP);
    float* img = out + (size_t)b*BOX*BOX;
    const float inv2s2 = 1.0f/(2.0f*1.5f*1.5f);

    #pragma unroll 1
    for (int p = 0; p < BPPT; p++) {
        const float aamp = sa[p];
        if (aamp == 0.f) continue;
        const float px0 = spx[p], px1 = spy[p];
        const float c0 = floorf(px0 + 0.5f);
        const float c1 = floorf(px1 + 0.5f);

        float w0a[KTAPS], w1a[KTAPS];
        int   i0a[KTAPS], i1a[KTAPS];
        #pragma unroll
        for (int k = 0; k < KTAPS; k++) {
            float g0 = c0 + (float)(k - HALF);
            float d0 = g0 - px0;
            float ww0 = __expf(-d0*d0*inv2s2);
            if (g0 < 0.f || g0 > (float)(BOX-1)) ww0 = 0.f;
            w0a[k] = ww0;
            i0a[k] = (int)fminf(fmaxf(g0, 0.f), (float)(BOX-1));

            float g1 = c1 + (float)(k - HALF);
            float d1 = g1 - px1;
            float ww1 = __expf(-d1*d1*inv2s2);
            if (g1 < 0.f || g1 > (float)(BOX-1)) ww1 = 0.f;
            w1a[k] = ww1;
            i1a[k] = (int)fminf(fmaxf(g1, 0.f), (float)(BOX-1));
        }

        if (lds_ok) {
            #pragma unroll
            for (int ky = 0; ky < KTAPS; ky++) {
                const float ay = aamp * w0a[ky];
                const int rbase = (i0a[ky] - lo0)*W1 - lo1;
                #pragma unroll
                for (int kx = 0; kx < KTAPS; kx++)
                    atomicAdd(&tile[rbase + i1a[kx]], ay * w1a[kx]);
            }
        } else {
            #pragma unroll
            for (int ky = 0; ky < KTAPS; ky++) {
                const float ay = aamp * w0a[ky];
                float* rowp = img + i0a[ky]*BOX;
                #pragma unroll
                for (int kx = 0; kx < KTAPS; kx++)
                    atomicAdd(&rowp[i1a[kx]], ay * w1a[kx]);
            }
        }
    }

    __syncthreads();

    if (lds_ok) {
        for (int rr = 0; rr < W0; rr++) {
            float* grow = img + (lo0 + rr)*BOX + lo1;
            const float* trow = tile + rr*W1;
            for (int cc = tid; cc < W1; cc += BTPB) {
                const float v = trow[cc];
                if (v != 0.f) atomicAdd(&grow[cc], v);
            }
        }
    }
}

__global__ __launch_bounds__(256) void copy_img(const float4* __restrict__ src,
                                                float4* __restrict__ dst, int n4)
{
    int i = blockIdx.x*blockDim.x + threadIdx.x;
    if (i < n4) dst[i] = src[i];
}

extern "C" void kernel_launch(void* const* d_in, const int* in_sizes, int n_in,
                              void* d_out, int out_size, void* d_ws, size_t ws_size,
                              hipStream_t stream)
{
    const float* z        = (const float*)d_in[0];
    const float* r        = (const float*)d_in[1];
    const float* posp     = (const float*)d_in[2];
    const float* amp      = (const float*)d_in[3];
    const float* lin0_w   = (const float*)d_in[4];
    const float* deform_w = (const float*)d_in[5];
    const float* deform_b = (const float*)d_in[6];
    const float* lin1a_w  = (const float*)d_in[7];
    const float* lin1b_w  = (const float*)d_in[8];
    const float* linamp_w = (const float*)d_in[9];
    const float* linamp_b = (const float*)d_in[10];
    const int*   dflag    = (const int*)d_in[11];
    float* out = (float*)d_out;

    hipMemsetAsync(out, 0, (size_t)IMG_ELEMS*sizeof(float), stream);

    dim3 gridA(ABLKX, BATCH);
    mlp_fwd<<<gridA, ATPB, 0, stream>>>(z, r, posp, lin0_w, deform_w, deform_b,
                                        lin1a_w, lin1b_w, dflag, out);

    dim3 gridB(BBLKX, BATCH);
    splat<<<gridB, BTPB, 0, stream>>>(z, amp, linamp_w, linamp_b, out);

    const int n4 = IMG_ELEMS/4;
    copy_img<<<(n4 + 255)/256, 256, 0, stream>>>((const float4*)out,
                                                 (float4*)(out + OFF_IMG2), n4);
}